// Round 1
// 440.622 us; speedup vs baseline: 1.2937x; 1.2937x over previous
//
#include <hip/hip_runtime.h>
#include <hip/hip_bf16.h>

using bf16 = __hip_bfloat16;
typedef float float4v __attribute__((ext_vector_type(4)));
typedef __bf16 bf16x8 __attribute__((ext_vector_type(8)));
typedef unsigned short ushort4v __attribute__((ext_vector_type(4)));
typedef unsigned short ushort8v __attribute__((ext_vector_type(8)));

#define B_  4
#define L_  4096
#define D_  2048
#define DI_ 256
#define M_  (B_*L_)       // 16384 rows
#define NC  64            // scan chunks per sequence
#define LC  (L_/NC)       // 64 steps per chunk

__device__ inline float bf2f(bf16 x) { return __bfloat162float(x); }
__device__ inline bf16  f2bf(float x) { return __float2bfloat16(x); }

__device__ inline void store4bf(bf16* p, float4v v) {
    ushort4v u;
#pragma unroll
    for (int i = 0; i < 4; i++) {
        bf16 h = f2bf(v[i]);
        u[i] = *(unsigned short*)&h;
    }
    *(ushort4v*)p = u;   // single 8B store
}

__device__ inline float4v load4bf(const bf16* p) {
    ushort4v u = *(const ushort4v*)p;
    float4v v;
#pragma unroll
    for (int i = 0; i < 4; i++) v[i] = __uint_as_float(((unsigned)u[i]) << 16);
    return v;
}

__device__ inline ushort8v cvt8(float4v a, float4v b) {
    ushort8v u;
#pragma unroll
    for (int i = 0; i < 4; i++) {
        bf16 h0 = f2bf(a[i]); u[i]     = *(unsigned short*)&h0;
        bf16 h1 = f2bf(b[i]); u[i + 4] = *(unsigned short*)&h1;
    }
    return u;
}

// async global->LDS, 16B per lane. LDS dest is wave-uniform base + lane*16;
// we pass the per-lane address matching exactly that layout.
__device__ __forceinline__ void gload_lds16(const bf16* g, bf16* l) {
    __builtin_amdgcn_global_load_lds((const __attribute__((address_space(1))) void*)(g),
                                     (__attribute__((address_space(3))) void*)(l),
                                     16, 0, 0);
}

// ---------------------------------------------------------------------------
// Transpose+convert: in fp32 [R,C] -> out bf16 [C+obase, R] rows (weights only)
// ---------------------------------------------------------------------------
__global__ void transpose_cvt(const float* __restrict__ in, bf16* __restrict__ out,
                              int R, int C, int obase) {
    int idx = blockIdx.x * 256 + threadIdx.x;
    if (idx < R * C) {
        int r = idx / C, c = idx - r * C;
        out[(size_t)(c + obase) * R + r] = f2bf(in[idx]);
    }
}

// ---------------------------------------------------------------------------
// MFMA GEMM: C[M,N] = A[M,K] x BT[N,K].  2-phase double-buffered pipeline:
//   prologue: stage tile0 -> barrier
//   iter t:   issue async stage(t+1) into buf^1; ds_read+MFMA buf; barrier
// Staging is global_load_lds (16B/lane) into LINEAR LDS [row][32k] bf16 with
// an XOR slot-swizzle realized by pre-swizzling the per-lane GLOBAL source:
//   LDS slot s of row r holds k-slot (s ^ ((r>>1)&3))   (slot = 8 bf16 = 16B)
// ds_read uses slot (quad ^ ((l15>>1)&3)) -> 2-way bank alias only (free).
// fp32-A path (AF32): reg-stage A (cvt fp32->bf16), ds_write into buf^1 after
// compute (no extra barrier needed); B still via global_load_lds.
// EPI: 0 = store bf16; 1 = delta/gate 4-way split (N=1024, aux=z);
//      2 = +fp32 residual (auxf = x), store bf16
// ---------------------------------------------------------------------------
#define BK 32

template<int TBM, int TBN, int EPI, bool AF32>
__global__ __launch_bounds__(256) void gemm_bt(const void* __restrict__ Av,
                                               const bf16* __restrict__ BT,
                                               int K, int N,
                                               bf16* __restrict__ o0, bf16* __restrict__ o1,
                                               bf16* __restrict__ o2, bf16* __restrict__ o3,
                                               const bf16* __restrict__ auxb,
                                               const float* __restrict__ auxf) {
    constexpr int MI  = TBM / 32, NI = TBN / 32, AP = TBM / 64, BP = TBN / 64;
    constexpr int ASZ = TBM * 32, BSZ = TBN * 32;   // bf16 elems per buffer
    __shared__ __align__(16) bf16 As[2 * ASZ];
    __shared__ __align__(16) bf16 Bs[2 * BSZ];
    const int tid  = threadIdx.x;
    const int bm   = blockIdx.x, bn = blockIdx.y;
    const int lane = tid & 63, wave = tid >> 6;
    const int wm   = (wave >> 1) * (TBM / 2), wn = (wave & 1) * (TBN / 2);
    const int l15  = lane & 15, quad = lane >> 4;
    const int rsub  = lane >> 2;                     // row within a 16-row stage instr
    const int kslot = (lane & 3) ^ ((lane >> 3) & 3); // pre-swizzled global k-slot
    const int sq    = quad ^ ((l15 >> 1) & 3);       // swizzled read slot
    const int sr    = tid >> 2, scs = tid & 3;       // AF32 staging row / k-slot
    const int swslot = scs ^ ((sr >> 1) & 3);        // AF32 swizzled write slot

    float4v acc[MI][NI] = {};
    const float* Af = (const float*)Av;
    const bf16*  Ab = (const bf16*)Av;
    float4v fa[AP][2];

    auto stage_a = [&](int buf, int kk) {            // bf16 A via DMA
#pragma unroll
        for (int p = 0; p < AP; p++) {
            int rbase = wave * (TBM / 4) + p * 16;
            gload_lds16(Ab + (size_t)(bm * TBM + rbase + rsub) * K + kk + kslot * 8,
                        As + buf * ASZ + rbase * 32 + lane * 8);
        }
    };
    auto stage_b = [&](int buf, int kk) {            // bf16 B via DMA
#pragma unroll
        for (int p = 0; p < BP; p++) {
            int rbase = wave * (TBN / 4) + p * 16;
            gload_lds16(BT + (size_t)(bn * TBN + rbase + rsub) * K + kk + kslot * 8,
                        Bs + buf * BSZ + rbase * 32 + lane * 8);
        }
    };
    auto load_a_f32 = [&](int kk) {                  // fp32 A -> regs
#pragma unroll
        for (int p = 0; p < AP; p++) {
            const float* src = Af + (size_t)(bm * TBM + p * 64 + sr) * K + kk + scs * 8;
            fa[p][0] = *(const float4v*)src;
            fa[p][1] = *(const float4v*)(src + 4);
        }
    };
    auto write_a_f32 = [&](int buf) {                // regs -> LDS (swizzled slot)
#pragma unroll
        for (int p = 0; p < AP; p++)
            *(ushort8v*)(As + buf * ASZ + (p * 64 + sr) * 32 + swslot * 8)
                = cvt8(fa[p][0], fa[p][1]);
    };
    auto compute = [&](int buf) {
        bf16x8 af[MI], bfr[NI];
#pragma unroll
        for (int mi = 0; mi < MI; mi++)
            af[mi] = *(const bf16x8*)(As + buf * ASZ + (wm + mi * 16 + l15) * 32 + sq * 8);
#pragma unroll
        for (int ni = 0; ni < NI; ni++)
            bfr[ni] = *(const bf16x8*)(Bs + buf * BSZ + (wn + ni * 16 + l15) * 32 + sq * 8);
#pragma unroll
        for (int mi = 0; mi < MI; mi++)
#pragma unroll
            for (int ni = 0; ni < NI; ni++)
                acc[mi][ni] = __builtin_amdgcn_mfma_f32_16x16x32_bf16(
                    bfr[ni], af[mi], acc[mi][ni], 0, 0, 0);
    };

    // prologue: stage tile 0 into buf 0
    if constexpr (AF32) load_a_f32(0); else stage_a(0, 0);
    stage_b(0, 0);
    if constexpr (AF32) write_a_f32(0);
    __syncthreads();   // drains vmcnt/lgkm: tile 0 resident

    const int nt = K / BK;
    int cur = 0;
    for (int t = 0; t < nt; t++) {
        if (t + 1 < nt) {
            if constexpr (AF32) load_a_f32((t + 1) * BK);
            else                stage_a(cur ^ 1, (t + 1) * BK);
            stage_b(cur ^ 1, (t + 1) * BK);
        }
        compute(cur);                     // hides stage(t+1) latency
        if (t + 1 < nt) {
            if constexpr (AF32) write_a_f32(cur ^ 1);
            __syncthreads();              // all reads of cur done + stage landed
        }
        cur ^= 1;
    }

    // Swapped layout: row(M) = l15-based, cols = quad*4 + reg (4 consecutive)
#pragma unroll
    for (int mi = 0; mi < MI; mi++) {
#pragma unroll
        for (int ni = 0; ni < NI; ni++) {
            int row = bm * TBM + wm + mi * 16 + l15;
            int col = bn * TBN + wn + ni * 16 + quad * 4;
            float4v v = acc[mi][ni];
            if (EPI == 0) {
                store4bf(o0 + (size_t)row * N + col, v);
            } else if (EPI == 1) {
                int sel = col >> 8, d = col & 255;
                bf16* dst = (sel == 0) ? o0 : (sel == 1) ? o1 : (sel == 2) ? o2 : o3;
                if (sel & 1) {   // gate = o * z
                    float4v z4 = load4bf(auxb + (size_t)row * DI_ + d);
#pragma unroll
                    for (int i = 0; i < 4; i++) v[i] *= z4[i];
                } else {         // delta = sigmoid(o)
#pragma unroll
                    for (int i = 0; i < 4; i++) v[i] = 1.f / (1.f + __expf(-v[i]));
                }
                store4bf(dst + (size_t)row * DI_ + d, v);
            } else {
                float4v r = *(const float4v*)(auxf + (size_t)row * N + col);
#pragma unroll
                for (int i = 0; i < 4; i++) v[i] += r[i];
                store4bf(o0 + (size_t)row * N + col, v);
            }
        }
    }
}

// ---------------------------------------------------------------------------
// Chunked linear-recurrence scan: h_t = delta_t * h_{t-1} + gate_t
// blockIdx.z = direction (0 fwd, 1 bwd/reversed)
// ---------------------------------------------------------------------------
__global__ __launch_bounds__(256) void scan_agg(const bf16* __restrict__ del_f,
                                                const bf16* __restrict__ gat_f,
                                                const bf16* __restrict__ del_b,
                                                const bf16* __restrict__ gat_b,
                                                float* __restrict__ aggA,
                                                float* __restrict__ aggB) {
    int c = blockIdx.x, b = blockIdx.y, dir = blockIdx.z, d = threadIdx.x;
    const bf16* delta = dir ? del_b : del_f;
    const bf16* gate  = dir ? gat_b : gat_f;
    float Ap = 1.f, h = 0.f;
    for (int i = 0; i < LC; i++) {
        int t = dir ? (L_ - 1 - (c * LC + i)) : (c * LC + i);
        size_t base = ((size_t)(b * L_ + t)) * DI_ + d;
        float dlt = bf2f(delta[base]);
        float g   = bf2f(gate[base]);
        Ap *= dlt;
        h = h * dlt + g;
    }
    size_t idx = (((size_t)dir * B_ + b) * NC + c) * DI_ + d;
    aggA[idx] = Ap;
    aggB[idx] = h;
}

__global__ void scan_mid(const float* __restrict__ aggA, const float* __restrict__ aggB,
                         float* __restrict__ Hin) {
    int b = blockIdx.x, dir = blockIdx.y, d = threadIdx.x;
    float h = 0.f;
    for (int c = 0; c < NC; c++) {
        size_t idx = (((size_t)dir * B_ + b) * NC + c) * DI_ + d;
        Hin[idx] = h;
        h = aggA[idx] * h + aggB[idx];
    }
}

__global__ __launch_bounds__(256) void scan_fix(const bf16* __restrict__ del_f,
                                                const bf16* __restrict__ gat_f,
                                                const bf16* __restrict__ del_b,
                                                const bf16* __restrict__ gat_b,
                                                const float* __restrict__ Hin,
                                                bf16* __restrict__ hcat) {
    int c = blockIdx.x, b = blockIdx.y, dir = blockIdx.z, d = threadIdx.x;
    const bf16* delta = dir ? del_b : del_f;
    const bf16* gate  = dir ? gat_b : gat_f;
    float h = Hin[(((size_t)dir * B_ + b) * NC + c) * DI_ + d];
    int colbase = dir * DI_;
    for (int i = 0; i < LC; i++) {
        int t = dir ? (L_ - 1 - (c * LC + i)) : (c * LC + i);
        size_t base = ((size_t)(b * L_ + t)) * DI_ + d;
        float dlt = bf2f(delta[base]);
        float g   = bf2f(gate[base]);
        h = h * dlt + g;
        hcat[((size_t)(b * L_ + t)) * (2 * DI_) + colbase + d] = f2bf(h);
    }
}

// ---------------------------------------------------------------------------
// LayerNorm over D=2048: reads bf16 ybuf, writes fp32 out. Fully vectorized.
// ---------------------------------------------------------------------------
__global__ __launch_bounds__(256) void ln_kernel(const bf16* __restrict__ y,
                                                 const float* __restrict__ gamma,
                                                 const float* __restrict__ beta,
                                                 float* __restrict__ outp) {
    __shared__ float ss[4], ssq[4];
    int row = blockIdx.x, tid = threadIdx.x;
    size_t base = (size_t)row * D_ + tid * 8;
    uint4 raw = *(const uint4*)(y + base);
    const unsigned short* u = (const unsigned short*)&raw;
    float v[8];
    float s = 0.f, sq = 0.f;
#pragma unroll
    for (int i = 0; i < 8; i++) {
        v[i] = __uint_as_float(((unsigned)u[i]) << 16);
        s += v[i];
        sq += v[i] * v[i];
    }
    for (int o = 32; o > 0; o >>= 1) { s += __shfl_down(s, o); sq += __shfl_down(sq, o); }
    if ((tid & 63) == 0) { ss[tid >> 6] = s; ssq[tid >> 6] = sq; }
    __syncthreads();
    float S  = ss[0] + ss[1] + ss[2] + ss[3];
    float SQ = ssq[0] + ssq[1] + ssq[2] + ssq[3];
    float mean = S * (1.f / D_);
    float var  = SQ * (1.f / D_) - mean * mean;
    float rstd = rsqrtf(var + 1e-5f);
    float4v g0 = *(const float4v*)(gamma + tid * 8);
    float4v g1 = *(const float4v*)(gamma + tid * 8 + 4);
    float4v b0 = *(const float4v*)(beta + tid * 8);
    float4v b1 = *(const float4v*)(beta + tid * 8 + 4);
    float4v r0, r1;
#pragma unroll
    for (int i = 0; i < 4; i++) {
        r0[i] = (v[i] - mean) * rstd * g0[i] + b0[i];
        r1[i] = (v[i + 4] - mean) * rstd * g1[i] + b1[i];
    }
    *(float4v*)(outp + base)     = r0;
    *(float4v*)(outp + base + 4) = r1;
}

// ---------------------------------------------------------------------------
extern "C" void kernel_launch(void* const* d_in, const int* in_sizes, int n_in,
                              void* d_out, int out_size, void* d_ws, size_t ws_size,
                              hipStream_t stream) {
    (void)in_sizes; (void)n_in; (void)out_size; (void)ws_size;
    const float* x     = (const float*)d_in[0];
    const float* W_in  = (const float*)d_in[1];
    const float* W_fwd = (const float*)d_in[2];
    const float* W_bwd = (const float*)d_in[3];
    const float* W_out = (const float*)d_in[4];
    const float* gamma = (const float*)d_in[5];
    const float* beta  = (const float*)d_in[6];
    float* out = (float*)d_out;

    char* ws = (char*)d_ws;
    size_t off = 0;
    auto alloc = [&](size_t bytes) -> char* {
        char* p = ws + off;
        off += (bytes + 255) & ~(size_t)255;
        return p;
    };
    bf16*  WinT   = (bf16*)alloc((size_t)DI_ * D_ * 2);           // [256, 2048]
    bf16*  WpT    = (bf16*)alloc((size_t)1024 * DI_ * 2);         // [1024, 256] fwd|bwd
    bf16*  WoutT  = (bf16*)alloc((size_t)D_ * 2 * DI_ * 2);       // [2048, 512]
    bf16*  z      = (bf16*)alloc((size_t)M_ * DI_ * 2);
    bf16*  del_f  = (bf16*)alloc((size_t)M_ * DI_ * 2);
    bf16*  gat_f  = (bf16*)alloc((size_t)M_ * DI_ * 2);
    bf16*  del_b  = (bf16*)alloc((size_t)M_ * DI_ * 2);
    bf16*  gat_b  = (bf16*)alloc((size_t)M_ * DI_ * 2);
    bf16*  hcat   = (bf16*)alloc((size_t)M_ * 2 * DI_ * 2);       // 16.8 MB
    bf16*  ybuf   = (bf16*)alloc((size_t)M_ * D_ * 2);            // 67 MB
    float* aggA   = (float*)alloc((size_t)2 * B_ * NC * DI_ * 4);
    float* aggB   = (float*)alloc((size_t)2 * B_ * NC * DI_ * 4);
    float* Hin    = (float*)alloc((size_t)2 * B_ * NC * DI_ * 4);

    // 1. weight transposes (fp32 -> bf16 [N,K])
    transpose_cvt<<<(D_ * DI_ + 255) / 256, 256, 0, stream>>>(W_in, WinT, D_, DI_, 0);
    transpose_cvt<<<(DI_ * 2 * DI_ + 255) / 256, 256, 0, stream>>>(W_fwd, WpT, DI_, 2 * DI_, 0);
    transpose_cvt<<<(DI_ * 2 * DI_ + 255) / 256, 256, 0, stream>>>(W_bwd, WpT, DI_, 2 * DI_, 2 * DI_);
    transpose_cvt<<<(2 * DI_ * D_ + 255) / 256, 256, 0, stream>>>(W_out, WoutT, 2 * DI_, D_, 0);

    // 2. GEMM1: z = x @ W_in  [16384 x 2048] x [2048 x 256], fp32 A staged->bf16
    gemm_bt<128, 64, 0, true><<<dim3(M_ / 128, DI_ / 64), 256, 0, stream>>>(
        x, WinT, D_, DI_, z, nullptr, nullptr, nullptr, nullptr, nullptr);

    // 3. GEMM2 fused dirs: o = z @ [W_fwd|W_bwd]; delta=sigmoid, gate=o*z
    gemm_bt<128, 128, 1, false><<<dim3(M_ / 128, 1024 / 128), 256, 0, stream>>>(
        z, WpT, DI_, 1024, del_f, gat_f, del_b, gat_b, z, nullptr);

    // 4. chunked scans (dir in blockIdx.z), write concat [h_f|h_b]
    scan_agg<<<dim3(NC, B_, 2), DI_, 0, stream>>>(del_f, gat_f, del_b, gat_b, aggA, aggB);
    scan_mid<<<dim3(B_, 2), DI_, 0, stream>>>(aggA, aggB, Hin);
    scan_fix<<<dim3(NC, B_, 2), DI_, 0, stream>>>(del_f, gat_f, del_b, gat_b, Hin, hcat);

    // 5. GEMM3: y = hcat @ W_out + x  [16384 x 512] x [512 x 2048] -> ybuf bf16
    gemm_bt<128, 128, 2, false><<<dim3(M_ / 128, D_ / 128), 256, 0, stream>>>(
        hcat, WoutT, 2 * DI_, D_, ybuf, nullptr, nullptr, nullptr, nullptr, x);

    // 6. LayerNorm: ybuf -> fp32 out
    ln_kernel<<<M_, 256, 0, stream>>>(ybuf, gamma, beta, out);
}